// Round 5
// baseline (181.307 us; speedup 1.0000x reference)
//
#include <hip/hip_runtime.h>

#define N_NODES 50000
#define E_EDGES 800000
#define IN_F 128
#define HC 128
#define NCOLS 512           // q|k|v|skip concatenated
#define ROWTILES 3125       // N_NODES/16
#define SCAN_BLOCKS 196     // ceil(50000/256)
#define PACK_BLOCKS 32
#define HIST_BLOCKS ((E_EDGES + 255) / 256)

typedef __attribute__((ext_vector_type(8))) short short8;
typedef __attribute__((ext_vector_type(4))) float floatx4;

__device__ __forceinline__ unsigned short f2bf(float f) {
    union { float f; unsigned u; } x; x.f = f;
    unsigned r = x.u + 0x7FFF + ((x.u >> 16) & 1);
    return (unsigned short)(r >> 16);
}
__device__ __forceinline__ float bflo(unsigned u) {
    union { unsigned u; float f; } c; c.u = u << 16; return c.f;
}
__device__ __forceinline__ float bfhi(unsigned u) {
    union { unsigned u; float f; } c; c.u = u & 0xFFFF0000u; return c.f;
}

// ---------------- fused: pack_w (blocks 0..31) | hist (blocks 32..) --------
__global__ __launch_bounds__(256) void pack_hist_k(
    const float* __restrict__ Wq, const float* __restrict__ Wk,
    const float* __restrict__ Wv, const float* __restrict__ Ws,
    const float* __restrict__ bq, const float* __restrict__ bk,
    const float* __restrict__ bv, const float* __restrict__ bs,
    short* __restrict__ bpack, float* __restrict__ bcat,
    const int* __restrict__ dst, int* __restrict__ cnt, int* __restrict__ rank)
{
    if (blockIdx.x < PACK_BLOCKS) {
        int t = blockIdx.x * 256 + threadIdx.x;    // 0..8191
        int lane = t & 63, ks = (t >> 6) & 3, nt = t >> 8;
        int col = nt * 16 + (lane & 15);
        int sec = col >> 7, c = col & 127;
        const float* W = sec == 0 ? Wq : sec == 1 ? Wk : sec == 2 ? Wv : Ws;
        int kbase = ks * 32 + (lane >> 4) * 8;
        short8 b;
#pragma unroll
        for (int j = 0; j < 8; j++) b[j] = (short)f2bf(W[(size_t)(kbase + j) * HC + c]);
        *(short8*)(bpack + (size_t)t * 8) = b;
        if (t < NCOLS) {
            int s2 = t >> 7, c2 = t & 127;
            bcat[t] = (s2 == 0 ? bq : s2 == 1 ? bk : s2 == 2 ? bv : bs)[c2];
        }
    } else {
        int e = (blockIdx.x - PACK_BLOCKS) * 256 + threadIdx.x;
        if (e < E_EDGES) rank[e] = atomicAdd(&cnt[dst[e]], 1);
    }
}

// ---------------- fused MFMA GEMM ------------------------------------------
__global__ __launch_bounds__(256) void gemm_mfma(
    const float* __restrict__ x, const short* __restrict__ bpack,
    const float* __restrict__ bcat,
    unsigned short* __restrict__ q, unsigned short* __restrict__ k,
    unsigned short* __restrict__ v, float* __restrict__ out)
{
    const int rt = blockIdx.x;
    const int cg = threadIdx.x >> 6;        // 0:q 1:k 2:v 3:skip
    const int lane = threadIdx.x & 63;
    const int m0 = rt * 16 + (lane & 15);
    const int koff = (lane >> 4) * 8;

    short8 a0[4];
#pragma unroll
    for (int ks = 0; ks < 4; ks++) {
        const float* p0 = x + (size_t)m0 * IN_F + ks * 32 + koff;
        float4 lo = *(const float4*)p0;
        float4 hi = *(const float4*)(p0 + 4);
        short8 a;
        a[0] = (short)f2bf(lo.x); a[1] = (short)f2bf(lo.y);
        a[2] = (short)f2bf(lo.z); a[3] = (short)f2bf(lo.w);
        a[4] = (short)f2bf(hi.x); a[5] = (short)f2bf(hi.y);
        a[6] = (short)f2bf(hi.z); a[7] = (short)f2bf(hi.w);
        a0[ks] = a;
    }

    unsigned short* dstb = (cg == 0) ? q : (cg == 1) ? k : v;
    const int rb0 = rt * 16 + (lane >> 4) * 4;

#pragma unroll
    for (int nt8 = 0; nt8 < 8; nt8++) {
        const int nt = cg * 8 + nt8;
        floatx4 acc = {0.f, 0.f, 0.f, 0.f};
#pragma unroll
        for (int ks = 0; ks < 4; ks++) {
            short8 b = *(const short8*)(bpack + ((size_t)(nt * 4 + ks) * 64 + lane) * 8);
            acc = __builtin_amdgcn_mfma_f32_16x16x32_bf16(a0[ks], b, acc, 0, 0, 0);
        }
        const int c = nt8 * 16 + (lane & 15);
        const float bias = bcat[cg * 128 + c];
        if (cg < 3) {
#pragma unroll
            for (int r = 0; r < 4; r++)
                dstb[(size_t)(rb0 + r) * HC + c] = f2bf(acc[r] + bias);
        } else {
#pragma unroll
            for (int r = 0; r < 4; r++)
                out[(size_t)(rb0 + r) * HC + c] = acc[r] + bias;
        }
    }
}

// ---------------- one-kernel scan: rowptr from cnt -------------------------
// Block b: prefix = sum(cnt[0 .. b*256)) read from L2, then block-local scan.
__global__ __launch_bounds__(256) void scan_apply(const int* __restrict__ cnt,
                                                  int* __restrict__ rowptr)
{
    __shared__ int wsum[4];
    const int t = threadIdx.x;
    const int lane = t & 63, w = t >> 6;
    const int limit = blockIdx.x * 256;

    int s = 0;
    for (int i = t; i < limit; i += 256) s += cnt[i];
#pragma unroll
    for (int off = 32; off >= 1; off >>= 1) s += __shfl_xor(s, off);
    if (lane == 0) wsum[w] = s;
    __syncthreads();
    const int prefix = wsum[0] + wsum[1] + wsum[2] + wsum[3];
    __syncthreads();

    int idx = limit + t;
    int val = (idx < N_NODES) ? cnt[idx] : 0;
    int incl = val;
#pragma unroll
    for (int off = 1; off < 64; off <<= 1) {
        int u = __shfl_up(incl, off);
        if (lane >= off) incl += u;
    }
    if (lane == 63) wsum[w] = incl;
    __syncthreads();
    int pre = 0;
#pragma unroll
    for (int i = 0; i < 4; i++) if (i < w) pre += wsum[i];
    int excl = prefix + pre + incl - val;
    if (idx < N_NODES) rowptr[idx] = excl;
    if (idx == N_NODES - 1) rowptr[N_NODES] = E_EDGES;
}

__global__ __launch_bounds__(256) void scatter_k(const int* __restrict__ src,
                                                 const int* __restrict__ dst,
                                                 const int* __restrict__ rowptr,
                                                 const int* __restrict__ rank,
                                                 int* __restrict__ ssrc)
{
    int e = blockIdx.x * 256 + threadIdx.x;
    if (e < E_EDGES) ssrc[rowptr[dst[e]] + rank[e]] = src[e];
}

// ---------------- per-node fused attention ---------------------------------
// 64 lanes = 4 edge-slots x 16 lanes. Lane (g,l16) covers channels l16*8..+8
// of edge e+g. Head h = l16>>2; quad (l16&~3) reduces the 32-ch dot with 2
// shfl_xor. Cross-slot combine once per node via shfl_xor 16/32.
__global__ __launch_bounds__(256) void node_attn(
    const unsigned short* __restrict__ q, const unsigned short* __restrict__ k,
    const unsigned short* __restrict__ v, const int* __restrict__ rowptr,
    const int* __restrict__ ssrc, float* __restrict__ out)
{
    const int wave = (blockIdx.x * 256 + threadIdx.x) >> 6;
    if (wave >= N_NODES) return;
    const int lane = threadIdx.x & 63;
    const int node = wave;
    const int g = lane >> 4;        // edge slot
    const int l16 = lane & 15;
    const int c0 = l16 * 8;         // my 8 channels

    const uint4 uq = *(const uint4*)(q + (size_t)node * HC + c0);
    float qf[8];
    qf[0] = bflo(uq.x); qf[1] = bfhi(uq.x);
    qf[2] = bflo(uq.y); qf[3] = bfhi(uq.y);
    qf[4] = bflo(uq.z); qf[5] = bfhi(uq.z);
    qf[6] = bflo(uq.w); qf[7] = bfhi(uq.w);

    float acc[8];
#pragma unroll
    for (int i = 0; i < 8; i++) acc[i] = 0.f;
    float ssum = 0.f;

    const int beg = __builtin_amdgcn_readfirstlane(rowptr[node]);
    const int end = __builtin_amdgcn_readfirstlane(rowptr[node + 1]);
    const float scale = 0.17677669529663687f;  // 1/sqrt(32)

    for (int e = beg; e < end; e += 4) {
        const int ee = e + g;
        const int jj = ssrc[ee < end ? ee : beg];
        const uint4 uk = *(const uint4*)(k + (size_t)jj * HC + c0);
        const uint4 uv = *(const uint4*)(v + (size_t)jj * HC + c0);

        float p = qf[0] * bflo(uk.x) + qf[1] * bfhi(uk.x)
                + qf[2] * bflo(uk.y) + qf[3] * bfhi(uk.y)
                + qf[4] * bflo(uk.z) + qf[5] * bfhi(uk.z)
                + qf[6] * bflo(uk.w) + qf[7] * bfhi(uk.w);
        p += __shfl_xor(p, 1);
        p += __shfl_xor(p, 2);
        float wgt = __expf(p * scale);
        wgt = (ee < end) ? wgt : 0.f;
        ssum += wgt;

        acc[0] += wgt * bflo(uv.x); acc[1] += wgt * bfhi(uv.x);
        acc[2] += wgt * bflo(uv.y); acc[3] += wgt * bfhi(uv.y);
        acc[4] += wgt * bflo(uv.z); acc[5] += wgt * bfhi(uv.z);
        acc[6] += wgt * bflo(uv.w); acc[7] += wgt * bfhi(uv.w);
    }

    // combine the 4 edge-slots
    ssum += __shfl_xor(ssum, 16);
    ssum += __shfl_xor(ssum, 32);
#pragma unroll
    for (int i = 0; i < 8; i++) {
        acc[i] += __shfl_xor(acc[i], 16);
        acc[i] += __shfl_xor(acc[i], 32);
    }

    if (g == 0) {
        const float inv = 1.0f / (ssum + 1e-16f);
        float* op = out + (size_t)node * HC + c0;
        float4 s0 = *(const float4*)op;
        float4 s1 = *(const float4*)(op + 4);
        float o[8];
        o[0] = acc[0] * inv + s0.x; o[1] = acc[1] * inv + s0.y;
        o[2] = acc[2] * inv + s0.z; o[3] = acc[3] * inv + s0.w;
        o[4] = acc[4] * inv + s1.x; o[5] = acc[5] * inv + s1.y;
        o[6] = acc[6] * inv + s1.z; o[7] = acc[7] * inv + s1.w;
#pragma unroll
        for (int i = 0; i < 8; i++) o[i] = o[i] >= 0.f ? o[i] : 0.2f * o[i];
        *(float4*)op       = make_float4(o[0], o[1], o[2], o[3]);
        *(float4*)(op + 4) = make_float4(o[4], o[5], o[6], o[7]);
    }
}

// ---------------- launch ---------------------------------------------------
extern "C" void kernel_launch(void* const* d_in, const int* in_sizes, int n_in,
                              void* d_out, int out_size, void* d_ws, size_t ws_size,
                              hipStream_t stream)
{
    const float* x    = (const float*)d_in[0];
    const int*   ei   = (const int*)d_in[1];
    const float* Wq   = (const float*)d_in[2];
    const float* bq   = (const float*)d_in[3];
    const float* Wk   = (const float*)d_in[4];
    const float* bk   = (const float*)d_in[5];
    const float* Wv   = (const float*)d_in[6];
    const float* bv   = (const float*)d_in[7];
    const float* Wsk  = (const float*)d_in[8];
    const float* bsk  = (const float*)d_in[9];
    float* out = (float*)d_out;

    char* w = (char*)d_ws;
    const size_t NFB = (size_t)N_NODES * HC * sizeof(unsigned short);
    unsigned short* q = (unsigned short*)w;            w += NFB;
    unsigned short* k = (unsigned short*)w;            w += NFB;
    unsigned short* v = (unsigned short*)w;            w += NFB;
    short* bpack = (short*)w;                          w += 8192 * 8 * sizeof(short);
    float* bcat  = (float*)w;                          w += NCOLS * sizeof(float);
    int* cnt    = (int*)w;                             w += N_NODES * sizeof(int);
    int* rowptr = (int*)w;                             w += (N_NODES + 1) * sizeof(int);
    int* rank   = (int*)w;                             w += (size_t)E_EDGES * sizeof(int);
    int* ssrc   = (int*)w;

    const int* srcIdx = ei;
    const int* dstIdx = ei + E_EDGES;

    hipMemsetAsync(cnt, 0, N_NODES * sizeof(int), stream);

    pack_hist_k<<<PACK_BLOCKS + HIST_BLOCKS, 256, 0, stream>>>(
        Wq, Wk, Wv, Wsk, bq, bk, bv, bsk, bpack, bcat, dstIdx, cnt, rank);
    gemm_mfma<<<ROWTILES, 256, 0, stream>>>(x, bpack, bcat, q, k, v, out);
    scan_apply<<<SCAN_BLOCKS, 256, 0, stream>>>(cnt, rowptr);
    scatter_k<<<(E_EDGES + 255) / 256, 256, 0, stream>>>(srcIdx, dstIdx, rowptr, rank, ssrc);
    node_attn<<<(N_NODES * 64) / 256, 256, 0, stream>>>(q, k, v, rowptr, ssrc, out);
}

// Round 6
// 174.547 us; speedup vs baseline: 1.0387x; 1.0387x over previous
//
#include <hip/hip_runtime.h>

#define N_NODES 50000
#define E_EDGES 800000
#define IN_F 128
#define HC 128
#define NCOLS 512           // q|k|v|skip concatenated
#define ROWTILES 3125       // N_NODES/16
#define SCAN_BLOCKS 196     // ceil(50000/256)
#define PACK_BLOCKS 32
#define HIST_BLOCKS ((E_EDGES + 255) / 256)

typedef __attribute__((ext_vector_type(8))) short short8;
typedef __attribute__((ext_vector_type(4))) float floatx4;

__device__ __forceinline__ unsigned short f2bf(float f) {
    union { float f; unsigned u; } x; x.f = f;
    unsigned r = x.u + 0x7FFF + ((x.u >> 16) & 1);
    return (unsigned short)(r >> 16);
}
__device__ __forceinline__ float bflo(unsigned u) {
    union { unsigned u; float f; } c; c.u = u << 16; return c.f;
}
__device__ __forceinline__ float bfhi(unsigned u) {
    union { unsigned u; float f; } c; c.u = u & 0xFFFF0000u; return c.f;
}

// ---------------- pack weights + zero cnt (32 blocks) ----------------------
__global__ __launch_bounds__(256) void pack_w(
    const float* __restrict__ Wq, const float* __restrict__ Wk,
    const float* __restrict__ Wv, const float* __restrict__ Ws,
    const float* __restrict__ bq, const float* __restrict__ bk,
    const float* __restrict__ bv, const float* __restrict__ bs,
    short* __restrict__ bpack, float* __restrict__ bcat,
    int* __restrict__ cnt)
{
    int t = blockIdx.x * 256 + threadIdx.x;    // 0..8191
    int lane = t & 63, ks = (t >> 6) & 3, nt = t >> 8;
    int col = nt * 16 + (lane & 15);
    int sec = col >> 7, c = col & 127;
    const float* W = sec == 0 ? Wq : sec == 1 ? Wk : sec == 2 ? Wv : Ws;
    int kbase = ks * 32 + (lane >> 4) * 8;
    short8 b;
#pragma unroll
    for (int j = 0; j < 8; j++) b[j] = (short)f2bf(W[(size_t)(kbase + j) * HC + c]);
    *(short8*)(bpack + (size_t)t * 8) = b;
    if (t < NCOLS) {
        int s2 = t >> 7, c2 = t & 127;
        bcat[t] = (s2 == 0 ? bq : s2 == 1 ? bk : s2 == 2 ? bv : bs)[c2];
    }
    for (int i = t; i < N_NODES; i += PACK_BLOCKS * 256) cnt[i] = 0;
}

// ---------------- fused: MFMA GEMM (blocks<ROWTILES) | hist (rest) ---------
__global__ __launch_bounds__(256) void gemm_hist(
    const float* __restrict__ x, const short* __restrict__ bpack,
    const float* __restrict__ bcat,
    unsigned short* __restrict__ q, unsigned short* __restrict__ k,
    unsigned short* __restrict__ v, float* __restrict__ out,
    const int* __restrict__ dst, int* __restrict__ cnt, int* __restrict__ rank)
{
    if (blockIdx.x >= ROWTILES) {
        int e = (blockIdx.x - ROWTILES) * 256 + threadIdx.x;
        if (e < E_EDGES) rank[e] = atomicAdd(&cnt[dst[e]], 1);
        return;
    }
    const int rt = blockIdx.x;
    const int cg = threadIdx.x >> 6;        // 0:q 1:k 2:v 3:skip
    const int lane = threadIdx.x & 63;
    const int m0 = rt * 16 + (lane & 15);
    const int koff = (lane >> 4) * 8;

    short8 a0[4];
#pragma unroll
    for (int ks = 0; ks < 4; ks++) {
        const float* p0 = x + (size_t)m0 * IN_F + ks * 32 + koff;
        float4 lo = *(const float4*)p0;
        float4 hi = *(const float4*)(p0 + 4);
        short8 a;
        a[0] = (short)f2bf(lo.x); a[1] = (short)f2bf(lo.y);
        a[2] = (short)f2bf(lo.z); a[3] = (short)f2bf(lo.w);
        a[4] = (short)f2bf(hi.x); a[5] = (short)f2bf(hi.y);
        a[6] = (short)f2bf(hi.z); a[7] = (short)f2bf(hi.w);
        a0[ks] = a;
    }

    unsigned short* dstb = (cg == 0) ? q : (cg == 1) ? k : v;
    const int rb0 = rt * 16 + (lane >> 4) * 4;

#pragma unroll
    for (int nt8 = 0; nt8 < 8; nt8++) {
        const int nt = cg * 8 + nt8;
        floatx4 acc = {0.f, 0.f, 0.f, 0.f};
#pragma unroll
        for (int ks = 0; ks < 4; ks++) {
            short8 b = *(const short8*)(bpack + ((size_t)(nt * 4 + ks) * 64 + lane) * 8);
            acc = __builtin_amdgcn_mfma_f32_16x16x32_bf16(a0[ks], b, acc, 0, 0, 0);
        }
        const int c = nt8 * 16 + (lane & 15);
        const float bias = bcat[cg * 128 + c];
        if (cg < 3) {
#pragma unroll
            for (int r = 0; r < 4; r++)
                dstb[(size_t)(rb0 + r) * HC + c] = f2bf(acc[r] + bias);
        } else {
#pragma unroll
            for (int r = 0; r < 4; r++)
                out[(size_t)(rb0 + r) * HC + c] = acc[r] + bias;
        }
    }
}

// ---------------- one-kernel scan: rowptr from cnt -------------------------
__global__ __launch_bounds__(256) void scan_apply(const int* __restrict__ cnt,
                                                  int* __restrict__ rowptr)
{
    __shared__ int wsum[4];
    const int t = threadIdx.x;
    const int lane = t & 63, w = t >> 6;
    const int limit = blockIdx.x * 256;

    int s = 0;
    for (int i = t; i < limit; i += 256) s += cnt[i];
#pragma unroll
    for (int off = 32; off >= 1; off >>= 1) s += __shfl_xor(s, off);
    if (lane == 0) wsum[w] = s;
    __syncthreads();
    const int prefix = wsum[0] + wsum[1] + wsum[2] + wsum[3];
    __syncthreads();

    int idx = limit + t;
    int val = (idx < N_NODES) ? cnt[idx] : 0;
    int incl = val;
#pragma unroll
    for (int off = 1; off < 64; off <<= 1) {
        int u = __shfl_up(incl, off);
        if (lane >= off) incl += u;
    }
    if (lane == 63) wsum[w] = incl;
    __syncthreads();
    int pre = 0;
#pragma unroll
    for (int i = 0; i < 4; i++) if (i < w) pre += wsum[i];
    int excl = prefix + pre + incl - val;
    if (idx < N_NODES) rowptr[idx] = excl;
    if (idx == N_NODES - 1) rowptr[N_NODES] = E_EDGES;
}

__global__ __launch_bounds__(256) void scatter_k(const int* __restrict__ src,
                                                 const int* __restrict__ dst,
                                                 const int* __restrict__ rowptr,
                                                 const int* __restrict__ rank,
                                                 int* __restrict__ ssrc)
{
    int e = blockIdx.x * 256 + threadIdx.x;
    if (e < E_EDGES) ssrc[rowptr[dst[e]] + rank[e]] = src[e];
}

// ---------------- per-node fused attention ---------------------------------
// 64 lanes = 8 edge-slots x 8 lanes. Lane (g,l8) covers channels l8*16..+16
// of edge e+g. Head h = l8>>1; pair (lane^1) completes the 32-ch head dot
// with ONE shfl_xor. Cross-slot combine once per node via xor 8/16/32.
__global__ __launch_bounds__(256) void node_attn(
    const unsigned short* __restrict__ q, const unsigned short* __restrict__ k,
    const unsigned short* __restrict__ v, const int* __restrict__ rowptr,
    const int* __restrict__ ssrc, float* __restrict__ out)
{
    const int wave = (blockIdx.x * 256 + threadIdx.x) >> 6;
    if (wave >= N_NODES) return;
    const int lane = threadIdx.x & 63;
    const int node = wave;
    const int g = lane >> 3;        // edge slot 0..7
    const int l8 = lane & 7;
    const int c0 = l8 * 16;         // my 16 channels

    const uint4 uq0 = *(const uint4*)(q + (size_t)node * HC + c0);
    const uint4 uq1 = *(const uint4*)(q + (size_t)node * HC + c0 + 8);

    float acc[16];
#pragma unroll
    for (int i = 0; i < 16; i++) acc[i] = 0.f;
    float ssum = 0.f;

    const int beg = __builtin_amdgcn_readfirstlane(rowptr[node]);
    const int end = __builtin_amdgcn_readfirstlane(rowptr[node + 1]);
    const float scale = 0.17677669529663687f;  // 1/sqrt(32)

    for (int e = beg; e < end; e += 8) {
        const int ee = e + g;
        const int jj = ssrc[ee < end ? ee : beg];
        const unsigned short* kp = k + (size_t)jj * HC + c0;
        const unsigned short* vp = v + (size_t)jj * HC + c0;
        const uint4 uk0 = *(const uint4*)kp;
        const uint4 uk1 = *(const uint4*)(kp + 8);
        const uint4 uv0 = *(const uint4*)vp;
        const uint4 uv1 = *(const uint4*)(vp + 8);

        float p = bflo(uq0.x) * bflo(uk0.x) + bfhi(uq0.x) * bfhi(uk0.x)
                + bflo(uq0.y) * bflo(uk0.y) + bfhi(uq0.y) * bfhi(uk0.y)
                + bflo(uq0.z) * bflo(uk0.z) + bfhi(uq0.z) * bfhi(uk0.z)
                + bflo(uq0.w) * bflo(uk0.w) + bfhi(uq0.w) * bfhi(uk0.w)
                + bflo(uq1.x) * bflo(uk1.x) + bfhi(uq1.x) * bfhi(uk1.x)
                + bflo(uq1.y) * bflo(uk1.y) + bfhi(uq1.y) * bfhi(uk1.y)
                + bflo(uq1.z) * bflo(uk1.z) + bfhi(uq1.z) * bfhi(uk1.z)
                + bflo(uq1.w) * bflo(uk1.w) + bfhi(uq1.w) * bfhi(uk1.w);
        p += __shfl_xor(p, 1);          // complete 32-ch head dot
        float wgt = __expf(p * scale);
        wgt = (ee < end) ? wgt : 0.f;
        ssum += wgt;

        acc[0]  += wgt * bflo(uv0.x); acc[1]  += wgt * bfhi(uv0.x);
        acc[2]  += wgt * bflo(uv0.y); acc[3]  += wgt * bfhi(uv0.y);
        acc[4]  += wgt * bflo(uv0.z); acc[5]  += wgt * bfhi(uv0.z);
        acc[6]  += wgt * bflo(uv0.w); acc[7]  += wgt * bfhi(uv0.w);
        acc[8]  += wgt * bflo(uv1.x); acc[9]  += wgt * bfhi(uv1.x);
        acc[10] += wgt * bflo(uv1.y); acc[11] += wgt * bfhi(uv1.y);
        acc[12] += wgt * bflo(uv1.z); acc[13] += wgt * bfhi(uv1.z);
        acc[14] += wgt * bflo(uv1.w); acc[15] += wgt * bfhi(uv1.w);
    }

    // combine the 8 edge-slots (lanes with same l8)
    ssum += __shfl_xor(ssum, 8);
    ssum += __shfl_xor(ssum, 16);
    ssum += __shfl_xor(ssum, 32);
#pragma unroll
    for (int i = 0; i < 16; i++) {
        acc[i] += __shfl_xor(acc[i], 8);
        acc[i] += __shfl_xor(acc[i], 16);
        acc[i] += __shfl_xor(acc[i], 32);
    }

    if (g == 0) {
        const float inv = 1.0f / (ssum + 1e-16f);
        float* op = out + (size_t)node * HC + c0;
        float o[16];
#pragma unroll
        for (int i = 0; i < 16; i += 4) {
            float4 s = *(const float4*)(op + i);
            o[i]     = acc[i]     * inv + s.x;
            o[i + 1] = acc[i + 1] * inv + s.y;
            o[i + 2] = acc[i + 2] * inv + s.z;
            o[i + 3] = acc[i + 3] * inv + s.w;
        }
#pragma unroll
        for (int i = 0; i < 16; i++) o[i] = o[i] >= 0.f ? o[i] : 0.2f * o[i];
#pragma unroll
        for (int i = 0; i < 16; i += 4)
            *(float4*)(op + i) = make_float4(o[i], o[i + 1], o[i + 2], o[i + 3]);
    }
}

// ---------------- launch ---------------------------------------------------
extern "C" void kernel_launch(void* const* d_in, const int* in_sizes, int n_in,
                              void* d_out, int out_size, void* d_ws, size_t ws_size,
                              hipStream_t stream)
{
    const float* x    = (const float*)d_in[0];
    const int*   ei   = (const int*)d_in[1];
    const float* Wq   = (const float*)d_in[2];
    const float* bq   = (const float*)d_in[3];
    const float* Wk   = (const float*)d_in[4];
    const float* bk   = (const float*)d_in[5];
    const float* Wv   = (const float*)d_in[6];
    const float* bv   = (const float*)d_in[7];
    const float* Wsk  = (const float*)d_in[8];
    const float* bsk  = (const float*)d_in[9];
    float* out = (float*)d_out;

    char* w = (char*)d_ws;
    const size_t NFB = (size_t)N_NODES * HC * sizeof(unsigned short);
    unsigned short* q = (unsigned short*)w;            w += NFB;
    unsigned short* k = (unsigned short*)w;            w += NFB;
    unsigned short* v = (unsigned short*)w;            w += NFB;
    short* bpack = (short*)w;                          w += 8192 * 8 * sizeof(short);
    float* bcat  = (float*)w;                          w += NCOLS * sizeof(float);
    int* cnt    = (int*)w;                             w += N_NODES * sizeof(int);
    int* rowptr = (int*)w;                             w += (N_NODES + 1) * sizeof(int);
    int* rank   = (int*)w;                             w += (size_t)E_EDGES * sizeof(int);
    int* ssrc   = (int*)w;

    const int* srcIdx = ei;
    const int* dstIdx = ei + E_EDGES;

    pack_w<<<PACK_BLOCKS, 256, 0, stream>>>(Wq, Wk, Wv, Wsk, bq, bk, bv, bsk,
                                            bpack, bcat, cnt);
    gemm_hist<<<ROWTILES + HIST_BLOCKS, 256, 0, stream>>>(
        x, bpack, bcat, q, k, v, out, dstIdx, cnt, rank);
    scan_apply<<<SCAN_BLOCKS, 256, 0, stream>>>(cnt, rowptr);
    scatter_k<<<(E_EDGES + 255) / 256, 256, 0, stream>>>(srcIdx, dstIdx, rowptr, rank, ssrc);
    node_attn<<<(N_NODES * 64) / 256, 256, 0, stream>>>(q, k, v, rowptr, ssrc, out);
}

// Round 7
// 173.775 us; speedup vs baseline: 1.0433x; 1.0044x over previous
//
#include <hip/hip_runtime.h>

#define N_NODES 50000
#define E_EDGES 800000
#define IN_F 128
#define HC 128
#define NCOLS 512           // q|k|v|skip concatenated
#define ROWTILES 3125       // N_NODES/16
#define SCAN_BLOCKS 196     // ceil(50000/256)
#define PACK_BLOCKS 32
#define HIST_BLOCKS ((E_EDGES + 255) / 256)

typedef __attribute__((ext_vector_type(8))) short short8;
typedef __attribute__((ext_vector_type(4))) float floatx4;

__device__ __forceinline__ unsigned short f2bf(float f) {
    union { float f; unsigned u; } x; x.f = f;
    unsigned r = x.u + 0x7FFF + ((x.u >> 16) & 1);
    return (unsigned short)(r >> 16);
}
__device__ __forceinline__ float bflo(unsigned u) {
    union { unsigned u; float f; } c; c.u = u << 16; return c.f;
}
__device__ __forceinline__ float bfhi(unsigned u) {
    union { unsigned u; float f; } c; c.u = u & 0xFFFF0000u; return c.f;
}

// ---------------- pack weights + zero cnt (32 blocks) ----------------------
__global__ __launch_bounds__(256) void pack_w(
    const float* __restrict__ Wq, const float* __restrict__ Wk,
    const float* __restrict__ Wv, const float* __restrict__ Ws,
    const float* __restrict__ bq, const float* __restrict__ bk,
    const float* __restrict__ bv, const float* __restrict__ bs,
    short* __restrict__ bpack, float* __restrict__ bcat,
    int* __restrict__ cnt)
{
    int t = blockIdx.x * 256 + threadIdx.x;    // 0..8191
    int lane = t & 63, ks = (t >> 6) & 3, nt = t >> 8;
    int col = nt * 16 + (lane & 15);
    int sec = col >> 7, c = col & 127;
    const float* W = sec == 0 ? Wq : sec == 1 ? Wk : sec == 2 ? Wv : Ws;
    int kbase = ks * 32 + (lane >> 4) * 8;
    short8 b;
#pragma unroll
    for (int j = 0; j < 8; j++) b[j] = (short)f2bf(W[(size_t)(kbase + j) * HC + c]);
    *(short8*)(bpack + (size_t)t * 8) = b;
    if (t < NCOLS) {
        int s2 = t >> 7, c2 = t & 127;
        bcat[t] = (s2 == 0 ? bq : s2 == 1 ? bk : s2 == 2 ? bv : bs)[c2];
    }
    for (int i = t; i < N_NODES; i += PACK_BLOCKS * 256) cnt[i] = 0;
}

// ---------------- fused: MFMA GEMM (blocks<ROWTILES) | hist (rest) ---------
// Epilogue: per-wave LDS transpose -> 1KB/inst coalesced global stores.
__global__ __launch_bounds__(256) void gemm_hist(
    const float* __restrict__ x, const short* __restrict__ bpack,
    const float* __restrict__ bcat,
    unsigned short* __restrict__ q, unsigned short* __restrict__ k,
    unsigned short* __restrict__ v, float* __restrict__ out,
    const int* __restrict__ dst, int* __restrict__ cnt, int* __restrict__ rank)
{
    if (blockIdx.x >= ROWTILES) {
        int e = (blockIdx.x - ROWTILES) * 256 + threadIdx.x;
        if (e < E_EDGES) rank[e] = atomicAdd(&cnt[dst[e]], 1);
        return;
    }
    __shared__ __align__(16) unsigned char lds_raw[3 * 4096 + 8192];

    const int rt = blockIdx.x;
    const int cg = threadIdx.x >> 6;        // 0:q 1:k 2:v 3:skip
    const int lane = threadIdx.x & 63;
    const int l16 = lane & 15;
    const int m0 = rt * 16 + l16;
    const int koff = (lane >> 4) * 8;

    short8 a0[4];
#pragma unroll
    for (int ks = 0; ks < 4; ks++) {
        const float* p0 = x + (size_t)m0 * IN_F + ks * 32 + koff;
        float4 lo = *(const float4*)p0;
        float4 hi = *(const float4*)(p0 + 4);
        short8 a;
        a[0] = (short)f2bf(lo.x); a[1] = (short)f2bf(lo.y);
        a[2] = (short)f2bf(lo.z); a[3] = (short)f2bf(lo.w);
        a[4] = (short)f2bf(hi.x); a[5] = (short)f2bf(hi.y);
        a[6] = (short)f2bf(hi.z); a[7] = (short)f2bf(hi.w);
        a0[ks] = a;
    }

    unsigned short* Lb = (unsigned short*)(lds_raw + cg * 4096);   // cg<3
    float*          Lf = (float*)(lds_raw + 12288);                // cg==3
    const int rrb = (lane >> 4) * 4;

#pragma unroll
    for (int nt8 = 0; nt8 < 8; nt8++) {
        const int nt = cg * 8 + nt8;
        floatx4 acc = {0.f, 0.f, 0.f, 0.f};
#pragma unroll
        for (int ks = 0; ks < 4; ks++) {
            short8 b = *(const short8*)(bpack + ((size_t)(nt * 4 + ks) * 64 + lane) * 8);
            acc = __builtin_amdgcn_mfma_f32_16x16x32_bf16(a0[ks], b, acc, 0, 0, 0);
        }
        const int c = nt8 * 16 + l16;
        const float bias = bcat[cg * 128 + c];
        if (cg < 3) {
#pragma unroll
            for (int r = 0; r < 4; r++)
                Lb[(rrb + r) * 128 + c] = f2bf(acc[r] + bias);
        } else {
#pragma unroll
            for (int r = 0; r < 4; r++)
                Lf[(rrb + r) * 128 + c] = acc[r] + bias;
        }
    }
    __syncthreads();

    if (cg < 3) {
        unsigned short* dstb = (cg == 0) ? q : (cg == 1) ? k : v;
        unsigned short* gout = dstb + (size_t)rt * 16 * HC;
#pragma unroll
        for (int rep = 0; rep < 4; rep++) {
            int idx = rep * 64 + lane;
            *(uint4*)(gout + idx * 8) = *(const uint4*)(Lb + idx * 8);
        }
    } else {
        float* gout = out + (size_t)rt * 16 * HC;
#pragma unroll
        for (int rep = 0; rep < 8; rep++) {
            int idx = rep * 64 + lane;
            *(float4*)(gout + idx * 4) = *(const float4*)(Lf + idx * 4);
        }
    }
}

// ---------------- one-kernel scan: rowptr from cnt -------------------------
__global__ __launch_bounds__(256) void scan_apply(const int* __restrict__ cnt,
                                                  int* __restrict__ rowptr)
{
    __shared__ int wsum[4];
    const int t = threadIdx.x;
    const int lane = t & 63, w = t >> 6;
    const int limit = blockIdx.x * 256;

    int s = 0;
    for (int i = t; i < limit; i += 256) s += cnt[i];
#pragma unroll
    for (int off = 32; off >= 1; off >>= 1) s += __shfl_xor(s, off);
    if (lane == 0) wsum[w] = s;
    __syncthreads();
    const int prefix = wsum[0] + wsum[1] + wsum[2] + wsum[3];
    __syncthreads();

    int idx = limit + t;
    int val = (idx < N_NODES) ? cnt[idx] : 0;
    int incl = val;
#pragma unroll
    for (int off = 1; off < 64; off <<= 1) {
        int u = __shfl_up(incl, off);
        if (lane >= off) incl += u;
    }
    if (lane == 63) wsum[w] = incl;
    __syncthreads();
    int pre = 0;
#pragma unroll
    for (int i = 0; i < 4; i++) if (i < w) pre += wsum[i];
    int excl = prefix + pre + incl - val;
    if (idx < N_NODES) rowptr[idx] = excl;
    if (idx == N_NODES - 1) rowptr[N_NODES] = E_EDGES;
}

__global__ __launch_bounds__(256) void scatter_k(const int* __restrict__ src,
                                                 const int* __restrict__ dst,
                                                 const int* __restrict__ rowptr,
                                                 const int* __restrict__ rank,
                                                 int* __restrict__ ssrc)
{
    int e = blockIdx.x * 256 + threadIdx.x;
    if (e < E_EDGES) ssrc[rowptr[dst[e]] + rank[e]] = src[e];
}

// ---------------- per-node fused attention ---------------------------------
// 64 lanes = 8 edge-slots x 8 lanes. Lane (g,l8) covers channels l8*16..+16
// of edge e+g. Pair (lane^1) completes the 32-ch head dot with ONE shfl_xor.
__global__ __launch_bounds__(256) void node_attn(
    const unsigned short* __restrict__ q, const unsigned short* __restrict__ k,
    const unsigned short* __restrict__ v, const int* __restrict__ rowptr,
    const int* __restrict__ ssrc, float* __restrict__ out)
{
    const int wave = (blockIdx.x * 256 + threadIdx.x) >> 6;
    if (wave >= N_NODES) return;
    const int lane = threadIdx.x & 63;
    const int node = wave;
    const int g = lane >> 3;        // edge slot 0..7
    const int l8 = lane & 7;
    const int c0 = l8 * 16;         // my 16 channels

    const uint4 uq0 = *(const uint4*)(q + (size_t)node * HC + c0);
    const uint4 uq1 = *(const uint4*)(q + (size_t)node * HC + c0 + 8);

    float acc[16];
#pragma unroll
    for (int i = 0; i < 16; i++) acc[i] = 0.f;
    float ssum = 0.f;

    const int beg = __builtin_amdgcn_readfirstlane(rowptr[node]);
    const int end = __builtin_amdgcn_readfirstlane(rowptr[node + 1]);
    const float scale = 0.17677669529663687f;  // 1/sqrt(32)

    for (int e = beg; e < end; e += 8) {
        const int ee = e + g;
        const int jj = ssrc[ee < end ? ee : beg];
        const unsigned short* kp = k + (size_t)jj * HC + c0;
        const unsigned short* vp = v + (size_t)jj * HC + c0;
        const uint4 uk0 = *(const uint4*)kp;
        const uint4 uk1 = *(const uint4*)(kp + 8);
        const uint4 uv0 = *(const uint4*)vp;
        const uint4 uv1 = *(const uint4*)(vp + 8);

        float p = bflo(uq0.x) * bflo(uk0.x) + bfhi(uq0.x) * bfhi(uk0.x)
                + bflo(uq0.y) * bflo(uk0.y) + bfhi(uq0.y) * bfhi(uk0.y)
                + bflo(uq0.z) * bflo(uk0.z) + bfhi(uq0.z) * bfhi(uk0.z)
                + bflo(uq0.w) * bflo(uk0.w) + bfhi(uq0.w) * bfhi(uk0.w)
                + bflo(uq1.x) * bflo(uk1.x) + bfhi(uq1.x) * bfhi(uk1.x)
                + bflo(uq1.y) * bflo(uk1.y) + bfhi(uq1.y) * bfhi(uk1.y)
                + bflo(uq1.z) * bflo(uk1.z) + bfhi(uq1.z) * bfhi(uk1.z)
                + bflo(uq1.w) * bflo(uk1.w) + bfhi(uq1.w) * bfhi(uk1.w);
        p += __shfl_xor(p, 1);          // complete 32-ch head dot
        float wgt = __expf(p * scale);
        wgt = (ee < end) ? wgt : 0.f;
        ssum += wgt;

        acc[0]  += wgt * bflo(uv0.x); acc[1]  += wgt * bfhi(uv0.x);
        acc[2]  += wgt * bflo(uv0.y); acc[3]  += wgt * bfhi(uv0.y);
        acc[4]  += wgt * bflo(uv0.z); acc[5]  += wgt * bfhi(uv0.z);
        acc[6]  += wgt * bflo(uv0.w); acc[7]  += wgt * bfhi(uv0.w);
        acc[8]  += wgt * bflo(uv1.x); acc[9]  += wgt * bfhi(uv1.x);
        acc[10] += wgt * bflo(uv1.y); acc[11] += wgt * bfhi(uv1.y);
        acc[12] += wgt * bflo(uv1.z); acc[13] += wgt * bfhi(uv1.z);
        acc[14] += wgt * bflo(uv1.w); acc[15] += wgt * bfhi(uv1.w);
    }

    ssum += __shfl_xor(ssum, 8);
    ssum += __shfl_xor(ssum, 16);
    ssum += __shfl_xor(ssum, 32);
#pragma unroll
    for (int i = 0; i < 16; i++) {
        acc[i] += __shfl_xor(acc[i], 8);
        acc[i] += __shfl_xor(acc[i], 16);
        acc[i] += __shfl_xor(acc[i], 32);
    }

    if (g == 0) {
        const float inv = 1.0f / (ssum + 1e-16f);
        float* op = out + (size_t)node * HC + c0;
        float o[16];
#pragma unroll
        for (int i = 0; i < 16; i += 4) {
            float4 s = *(const float4*)(op + i);
            o[i]     = acc[i]     * inv + s.x;
            o[i + 1] = acc[i + 1] * inv + s.y;
            o[i + 2] = acc[i + 2] * inv + s.z;
            o[i + 3] = acc[i + 3] * inv + s.w;
        }
#pragma unroll
        for (int i = 0; i < 16; i++) o[i] = o[i] >= 0.f ? o[i] : 0.2f * o[i];
#pragma unroll
        for (int i = 0; i < 16; i += 4)
            *(float4*)(op + i) = make_float4(o[i], o[i + 1], o[i + 2], o[i + 3]);
    }
}

// ---------------- launch ---------------------------------------------------
extern "C" void kernel_launch(void* const* d_in, const int* in_sizes, int n_in,
                              void* d_out, int out_size, void* d_ws, size_t ws_size,
                              hipStream_t stream)
{
    const float* x    = (const float*)d_in[0];
    const int*   ei   = (const int*)d_in[1];
    const float* Wq   = (const float*)d_in[2];
    const float* bq   = (const float*)d_in[3];
    const float* Wk   = (const float*)d_in[4];
    const float* bk   = (const float*)d_in[5];
    const float* Wv   = (const float*)d_in[6];
    const float* bv   = (const float*)d_in[7];
    const float* Wsk  = (const float*)d_in[8];
    const float* bsk  = (const float*)d_in[9];
    float* out = (float*)d_out;

    char* w = (char*)d_ws;
    const size_t NFB = (size_t)N_NODES * HC * sizeof(unsigned short);
    unsigned short* q = (unsigned short*)w;            w += NFB;
    unsigned short* k = (unsigned short*)w;            w += NFB;
    unsigned short* v = (unsigned short*)w;            w += NFB;
    short* bpack = (short*)w;                          w += 8192 * 8 * sizeof(short);
    float* bcat  = (float*)w;                          w += NCOLS * sizeof(float);
    int* cnt    = (int*)w;                             w += N_NODES * sizeof(int);
    int* rowptr = (int*)w;                             w += (N_NODES + 1) * sizeof(int);
    int* rank   = (int*)w;                             w += (size_t)E_EDGES * sizeof(int);
    int* ssrc   = (int*)w;

    const int* srcIdx = ei;
    const int* dstIdx = ei + E_EDGES;

    pack_w<<<PACK_BLOCKS, 256, 0, stream>>>(Wq, Wk, Wv, Wsk, bq, bk, bv, bsk,
                                            bpack, bcat, cnt);
    gemm_hist<<<ROWTILES + HIST_BLOCKS, 256, 0, stream>>>(
        x, bpack, bcat, q, k, v, out, dstIdx, cnt, rank);
    scan_apply<<<SCAN_BLOCKS, 256, 0, stream>>>(cnt, rowptr);
    scatter_k<<<(E_EDGES + 255) / 256, 256, 0, stream>>>(srcIdx, dstIdx, rowptr, rank, ssrc);
    node_attn<<<(N_NODES * 64) / 256, 256, 0, stream>>>(q, k, v, rowptr, ssrc, out);
}